// Round 1
// baseline (479.247 us; speedup 1.0000x reference)
//
#include <hip/hip_runtime.h>
#include <hip/hip_bf16.h>

// Problem constants (B,C,H,W = 4,512,64,64; A=64; N=H*W=4096)
constexpr int BB = 4;
constexpr int C  = 512;
constexpr int A  = 64;
constexpr int N  = 4096;

typedef __attribute__((ext_vector_type(8))) short s16x8;   // 8 bf16 (4 VGPRs)
typedef __attribute__((ext_vector_type(4))) float f32x4;   // 4 fp32 acc

#define MFMA_16x16x32_BF16(a, b, c) __builtin_amdgcn_mfma_f32_16x16x32_bf16((a), (b), (c), 0, 0, 0)

typedef __attribute__((address_space(3))) unsigned int lds_u32_t;
typedef const __attribute__((address_space(1))) unsigned int glb_u32_t;

__device__ __forceinline__ void gl2lds16(const void* g, void* l) {
    // async global->LDS, 16B/lane; LDS dest = wave-uniform base + lane*16
    __builtin_amdgcn_global_load_lds((glb_u32_t*)g, (lds_u32_t*)l, 16, 0, 0);
}

// ---------------------------------------------------------------------------
// K0a: transpose + fp32->bf16. src [z][K][M] fp32 -> dst [z][M][K] bf16.
__global__ __launch_bounds__(256) void k_trans(const float* __restrict__ src,
                                               __hip_bfloat16* __restrict__ dst,
                                               int K, int M) {
    __shared__ __hip_bfloat16 Ls[64][66];
    int m0 = blockIdx.x << 6, k0 = blockIdx.y << 6;
    size_t bo = (size_t)blockIdx.z * K * M;
    int t = threadIdx.x;
    int lm = t & 63, g = t >> 6;
    #pragma unroll
    for (int j = 0; j < 16; ++j) {
        int kk = j * 4 + g;
        Ls[kk][lm] = __float2bfloat16(src[bo + (size_t)(k0 + kk) * M + m0 + lm]);
    }
    __syncthreads();
    #pragma unroll
    for (int j = 0; j < 16; ++j) {
        int mm = j * 4 + g;
        dst[bo + (size_t)(m0 + mm) * K + k0 + lm] = Ls[lm][mm];
    }
}

// ---------------------------------------------------------------------------
// K0b: transpose + hi/lo bf16 split. src [z][K][M] fp32 -> dhi/dlo [z][M][K].
// fp32 LDS tile (65 pad -> conflict-free column reads), split at write.
__global__ __launch_bounds__(256) void k_trans2(const float* __restrict__ src,
                                                __hip_bfloat16* __restrict__ dhi,
                                                __hip_bfloat16* __restrict__ dlo,
                                                int K, int M) {
    __shared__ float Ls[64][65];
    int m0 = blockIdx.x << 6, k0 = blockIdx.y << 6;
    size_t bo = (size_t)blockIdx.z * K * M;
    int t = threadIdx.x;
    int lm = t & 63, g = t >> 6;
    #pragma unroll
    for (int j = 0; j < 16; ++j) {
        int kk = j * 4 + g;
        Ls[kk][lm] = src[bo + (size_t)(k0 + kk) * M + m0 + lm];
    }
    __syncthreads();
    #pragma unroll
    for (int j = 0; j < 16; ++j) {
        int mm = j * 4 + g;
        float v = Ls[lm][mm];
        __hip_bfloat16 h = __float2bfloat16(v);
        size_t idx = bo + (size_t)(m0 + mm) * K + k0 + lm;
        dhi[idx] = h;
        dlo[idx] = __float2bfloat16(v - __bfloat162float(h));
    }
}

// ---------------------------------------------------------------------------
// K1 v2 (k_fgm): f,g convs as ONE split-precision MFMA GEMM.
// out[row][col] , row = b*N+n (64/block), col = [f 0..63 | g 64..127].
// 3-product split (Ah*Bh + Al*Bh + Ah*Bl) -> ~2^-18 relative, matches the old
// fp32 path. Epilogue adds bias and emits hi/lo bf16 for k_so.
// grid 256 x 256 (4 waves: mh=w&1 over 2x32 rows, nh=w>>1 over 2x64 cols).
__global__ __launch_bounds__(256) void k_fgm(const __hip_bfloat16* __restrict__ XThi, const __hip_bfloat16* __restrict__ XTlo,
                                             const __hip_bfloat16* __restrict__ WfThi, const __hip_bfloat16* __restrict__ WfTlo,
                                             const __hip_bfloat16* __restrict__ WgThi, const __hip_bfloat16* __restrict__ WgTlo,
                                             const float* __restrict__ bfv, const float* __restrict__ bgv,
                                             __hip_bfloat16* __restrict__ FFhi, __hip_bfloat16* __restrict__ FFlo,
                                             __hip_bfloat16* __restrict__ GFhi, __hip_bfloat16* __restrict__ GFlo) {
    __shared__ __align__(16) __hip_bfloat16 Ah[64 * 32], Al[64 * 32];    // 4+4 KB
    __shared__ __align__(16) __hip_bfloat16 Bh[128 * 32], Bl[128 * 32];  // 8+8 KB
    int r0 = blockIdx.x << 6;           // global row base (b*N+n), 0..16320
    int t = threadIdx.x;
    int w = t >> 6, l = t & 63;
    int ln15 = l & 15, quad = l >> 4;
    int mh = w & 1, nh = w >> 1;

    f32x4 acc[2][4];
    #pragma unroll
    for (int mi = 0; mi < 2; ++mi)
        #pragma unroll
        for (int ni = 0; ni < 4; ++ni) acc[mi][ni] = (f32x4){0.f, 0.f, 0.f, 0.f};

    for (int kt = 0; kt < C; kt += 32) {
        {   // A tiles: 64 rows x 32 k, hi+lo, XOR-rotation swizzled segs
            int row = t >> 2, seg = t & 3;
            int gseg = (seg - (row >> 1)) & 3;
            size_t go = (size_t)(r0 + row) * C + kt + gseg * 8;
            gl2lds16(XThi + go, &Ah[t * 8]);
            gl2lds16(XTlo + go, &Al[t * 8]);
        }
        #pragma unroll
        for (int j = 0; j < 2; ++j) {   // B tiles: rows 0-63 = WfT, 64-127 = WgT
            int i = j * 256 + t;
            int row = i >> 2, seg = i & 3;
            int gseg = (seg - (row >> 1)) & 3;
            size_t go = (size_t)(row & 63) * C + kt + gseg * 8;
            const __hip_bfloat16* bh = j ? WgThi : WfThi;
            const __hip_bfloat16* bl = j ? WgTlo : WfTlo;
            gl2lds16(bh + go, &Bh[i * 8]);
            gl2lds16(bl + go, &Bl[i * 8]);
        }
        __syncthreads();
        s16x8 afh[2], afl[2], bfh[4], bfl[4];
        #pragma unroll
        for (int mi = 0; mi < 2; ++mi) {
            int row = mh * 32 + mi * 16 + ln15;
            int sw = ((quad + (row >> 1)) & 3) << 3;
            afh[mi] = *(const s16x8*)&Ah[row * 32 + sw];
            afl[mi] = *(const s16x8*)&Al[row * 32 + sw];
        }
        #pragma unroll
        for (int ni = 0; ni < 4; ++ni) {
            int row = nh * 64 + ni * 16 + ln15;
            int sw = ((quad + (row >> 1)) & 3) << 3;
            bfh[ni] = *(const s16x8*)&Bh[row * 32 + sw];
            bfl[ni] = *(const s16x8*)&Bl[row * 32 + sw];
        }
        #pragma unroll
        for (int mi = 0; mi < 2; ++mi)
            #pragma unroll
            for (int ni = 0; ni < 4; ++ni) {
                acc[mi][ni] = MFMA_16x16x32_BF16(afh[mi], bfh[ni], acc[mi][ni]);
                acc[mi][ni] = MFMA_16x16x32_BF16(afl[mi], bfh[ni], acc[mi][ni]);
                acc[mi][ni] = MFMA_16x16x32_BF16(afh[mi], bfl[ni], acc[mi][ni]);
            }
        __syncthreads();
    }

    #pragma unroll
    for (int mi = 0; mi < 2; ++mi) {
        #pragma unroll
        for (int r = 0; r < 4; ++r) {
            size_t grow = (size_t)(r0 + mh * 32 + mi * 16 + quad * 4 + r) * A;
            #pragma unroll
            for (int ni = 0; ni < 4; ++ni) {
                int col = nh * 64 + ni * 16 + ln15;     // nh selects f vs g (wave-uniform)
                if (col < A) {
                    float v = acc[mi][ni][r] + bfv[col];
                    __hip_bfloat16 h = __float2bfloat16(v);
                    FFhi[grow + col] = h;
                    FFlo[grow + col] = __float2bfloat16(v - __bfloat162float(h));
                } else {
                    int a = col - A;
                    float v = acc[mi][ni][r] + bgv[a];
                    __hip_bfloat16 h = __float2bfloat16(v);
                    GFhi[grow + a] = h;
                    GFlo[grow + a] = __float2bfloat16(v - __bfloat162float(h));
                }
            }
        }
    }
}

// ---------------------------------------------------------------------------
// K2: h conv as bf16 MFMA GEMM. HFT[c][n] = sum_k WhT[c][k]*XT[b][n][k] + bh[c].
// grid (C/128, N/128, BB) x 256.
__global__ __launch_bounds__(256) void k_hm(const __hip_bfloat16* __restrict__ WhT,
                                            const __hip_bfloat16* __restrict__ XT,
                                            const float* __restrict__ bhv,
                                            __hip_bfloat16* __restrict__ HFT) {
    __shared__ __align__(16) __hip_bfloat16 As[128 * 32];
    __shared__ __align__(16) __hip_bfloat16 Bs[128 * 32];
    int b  = blockIdx.z;
    int c0 = blockIdx.x << 7;
    int n0 = blockIdx.y << 7;
    int t = threadIdx.x;
    int w = t >> 6, l = t & 63;
    int ln15 = l & 15, quad = l >> 4;
    int mc = (w >> 1) << 6, nn = (w & 1) << 6;

    const __hip_bfloat16* Bb = XT + (size_t)b * N * C;   // [4096, 512]

    f32x4 acc[4][4];
    #pragma unroll
    for (int mi = 0; mi < 4; ++mi)
        #pragma unroll
        for (int ni = 0; ni < 4; ++ni) acc[mi][ni] = (f32x4){0.f, 0.f, 0.f, 0.f};

    for (int kt = 0; kt < C; kt += 32) {
        #pragma unroll
        for (int j = 0; j < 2; ++j) {
            int i = j * 256 + t;
            int row = i >> 2, seg = i & 3;
            int gseg = (seg - (row >> 1)) & 3;
            gl2lds16(WhT + ((size_t)(c0 + row) * C + kt + gseg * 8), &As[i * 8]);
        }
        #pragma unroll
        for (int j = 0; j < 2; ++j) {
            int i = j * 256 + t;
            int row = i >> 2, seg = i & 3;
            int gseg = (seg - (row >> 1)) & 3;
            gl2lds16(Bb + ((size_t)(n0 + row) * C + kt + gseg * 8), &Bs[i * 8]);
        }
        __syncthreads();
        s16x8 af[4], bf2[4];
        #pragma unroll
        for (int mi = 0; mi < 4; ++mi) {
            int row = mc + mi * 16 + ln15;
            int sw = ((quad + (row >> 1)) & 3) << 3;
            af[mi] = *(const s16x8*)&As[row * 32 + sw];
        }
        #pragma unroll
        for (int ni = 0; ni < 4; ++ni) {
            int row = nn + ni * 16 + ln15;
            int sw = ((quad + (row >> 1)) & 3) << 3;
            bf2[ni] = *(const s16x8*)&Bs[row * 32 + sw];
        }
        #pragma unroll
        for (int mi = 0; mi < 4; ++mi)
            #pragma unroll
            for (int ni = 0; ni < 4; ++ni)
                acc[mi][ni] = MFMA_16x16x32_BF16(af[mi], bf2[ni], acc[mi][ni]);
        __syncthreads();
    }

    #pragma unroll
    for (int mi = 0; mi < 4; ++mi) {
        #pragma unroll
        for (int r = 0; r < 4; ++r) {
            int c = c0 + mc + mi * 16 + quad * 4 + r;
            float bias = bhv[c];
            size_t rowbase = ((size_t)b * C + c) * N;
            #pragma unroll
            for (int ni = 0; ni < 4; ++ni) {
                int n = n0 + nn + ni * 16 + ln15;
                HFT[rowbase + n] = __float2bfloat16(acc[mi][ni][r] + bias);
            }
        }
    }
}

// ---------------------------------------------------------------------------
// K3 (k_so): FUSED S -> exp -> PV -> epilogue. Replaces k_s + k_o; P is never
// materialized in HBM (saves the 134 MB write + 134 MB read round-trip).
//
// Block = 32 queries x full C=512, batch b. 256 threads = 4 waves.
//   QK phase: wave w = key-quarter of the 64-key chunk (keys w*16..w*16+15).
//             S = split-precision (6 MFMA / 16x16 tile), exp (no max shift:
//             same justification as the old k_s header), P -> 4 KB LDS tile.
//   PV phase: wave w = c-slice w*128..w*128+127; A-frags from P_lds, B-frags
//             (H) straight from global (each H row consumed by exactly ONE
//             wave -> no staging benefit; HFT[b] = 4 MB = one XCD's L2).
//   rowsum finalized in-block -> epilogue out = scale*O/rowsum + x fused.
//
// P_lds swizzle: row q = 128 B (64 keys bf16); byte ^= (q&7)<<4.
//   write (b16, key=ln15): quads pair up -> 4-way on 8 tiny stores (cheap);
//   read (b128, q=ln15):   2 lanes/16B-slot -> 2-way = free (m136).
//   XOR flips bits 4-6 only; reads are 16B-aligned so (u^v)+j == (u+j)^v,
//   i.e. the b128 read returns keys ks*32+quad*8+0..7 in order.
//
// Grid 512 = 4b x 128qs, XCD-pinned: batch b lives on XCDs {2b, 2b+1} so its
// 4 MB HFT stays L2-resident (decode below is bijective over (b,qs)).
__global__ __launch_bounds__(256) void k_so(const __hip_bfloat16* __restrict__ GFhi, const __hip_bfloat16* __restrict__ GFlo,
                                            const __hip_bfloat16* __restrict__ FFhi, const __hip_bfloat16* __restrict__ FFlo,
                                            const __hip_bfloat16* __restrict__ HFT,
                                            const float* __restrict__ x,
                                            const float* __restrict__ scalep,
                                            float* __restrict__ out) {
    __shared__ __align__(16) __hip_bfloat16 Pl[32 * 64];   // 4 KB swizzled P tile
    __shared__ float sred[4][32];
    __shared__ float rsum[32];

    int id  = blockIdx.x;
    int xcd = id & 7;                         // HW round-robins blocks over 8 XCDs
    int b   = xcd >> 1;                       // batch pinned to an XCD pair
    int qs  = ((id >> 3) << 1) | (xcd & 1);   // 0..127, bijective with id
    int q0  = qs << 5;

    int t = threadIdx.x;
    int w = t >> 6, l = t & 63;
    int ln15 = l & 15, quad = l >> 4, q8 = quad << 3;

    const __hip_bfloat16* Fh = FFhi + (size_t)b * N * A;
    const __hip_bfloat16* Fl = FFlo + (size_t)b * N * A;
    const __hip_bfloat16* Hb = HFT  + (size_t)b * C * N;

    // G A-frags (queries, held all kernel): lane m=ln15, k=quad*8+j; hi+lo
    s16x8 ah[2][2], al[2][2];
    #pragma unroll
    for (int mi = 0; mi < 2; ++mi) {
        const __hip_bfloat16* gp = GFhi + (size_t)(b * N + q0 + mi * 16 + ln15) * A + q8;
        const __hip_bfloat16* lp = GFlo + (size_t)(b * N + q0 + mi * 16 + ln15) * A + q8;
        ah[mi][0] = *(const s16x8*)gp; ah[mi][1] = *(const s16x8*)(gp + 32);
        al[mi][0] = *(const s16x8*)lp; al[mi][1] = *(const s16x8*)(lp + 32);
    }

    f32x4 acc[2][8];                            // O acc: 32q x 128c per wave
    #pragma unroll
    for (int mi = 0; mi < 2; ++mi)
        #pragma unroll
        for (int ni = 0; ni < 8; ++ni) acc[mi][ni] = (f32x4){0.f, 0.f, 0.f, 0.f};
    float sm[2][4] = {{0.f,0.f,0.f,0.f},{0.f,0.f,0.f,0.f}};

    char* Pb = (char*)&Pl[0];

    for (int kt = 0; kt < N; kt += 64) {
        // (1) F key-frags FIRST: the QK waitcnt then leaves the hb loads in flight
        const __hip_bfloat16* fr  = Fh + (size_t)(kt + w * 16 + ln15) * A + q8;
        const __hip_bfloat16* flr = Fl + (size_t)(kt + w * 16 + ln15) * A + q8;
        s16x8 kh0 = *(const s16x8*)fr;
        s16x8 kh1 = *(const s16x8*)(fr + 32);
        s16x8 kl0 = *(const s16x8*)flr;
        s16x8 kl1 = *(const s16x8*)(flr + 32);
        // (2) H c-frags for this chunk's PV (both 32-key halves), issued early;
        //     their latency hides under the whole QK phase.
        s16x8 hb[2][8];
        #pragma unroll
        for (int ks = 0; ks < 2; ++ks)
            #pragma unroll
            for (int ni = 0; ni < 8; ++ni)
                hb[ks][ni] = *(const s16x8*)&Hb[(size_t)(w * 128 + ni * 16 + ln15) * N + kt + ks * 32 + q8];
        // (3) S = G.F^T (split precision), exp, stash P in LDS
        #pragma unroll
        for (int mi = 0; mi < 2; ++mi) {
            f32x4 s = {0.f, 0.f, 0.f, 0.f};
            s = MFMA_16x16x32_BF16(ah[mi][0], kh0, s);
            s = MFMA_16x16x32_BF16(ah[mi][1], kh1, s);
            s = MFMA_16x16x32_BF16(al[mi][0], kh0, s);
            s = MFMA_16x16x32_BF16(al[mi][1], kh1, s);
            s = MFMA_16x16x32_BF16(ah[mi][0], kl0, s);
            s = MFMA_16x16x32_BF16(ah[mi][1], kl1, s);
            int key2 = (w * 16 + ln15) << 1;        // byte offset of this key
            #pragma unroll
            for (int r = 0; r < 4; ++r) {
                int q = mi * 16 + quad * 4 + r;
                float p = __expf(s[r]);             // no max shift (see k_s note)
                __hip_bfloat16 pb = __float2bfloat16(p);
                sm[mi][r] += __bfloat162float(pb);  // sum what we actually use
                *(__hip_bfloat16*)(Pb + q * 128 + (key2 ^ ((q & 7) << 4))) = pb;
            }
        }
        __syncthreads();                            // P ready for all waves
        // (4) O += P @ H^T  (wave = its c-slice; full P tile from LDS)
        #pragma unroll
        for (int ks = 0; ks < 2; ++ks) {
            s16x8 pa[2];
            #pragma unroll
            for (int mi = 0; mi < 2; ++mi) {
                int q = mi * 16 + ln15;
                pa[mi] = *(const s16x8*)(Pb + q * 128 + ((ks * 64 + quad * 16) ^ ((q & 7) << 4)));
            }
            #pragma unroll
            for (int mi = 0; mi < 2; ++mi)
                #pragma unroll
                for (int ni = 0; ni < 8; ++ni)
                    acc[mi][ni] = MFMA_16x16x32_BF16(pa[mi], hb[ks][ni], acc[mi][ni]);
        }
        __syncthreads();                            // P consumed; next QK may overwrite
    }

    // rowsum: per-lane partials -> 16-lane (key) reduce -> across kq waves via LDS
    #pragma unroll
    for (int mi = 0; mi < 2; ++mi)
        #pragma unroll
        for (int r = 0; r < 4; ++r)
            #pragma unroll
            for (int d = 1; d < 16; d <<= 1)
                sm[mi][r] += __shfl_xor(sm[mi][r], d, 64);
    if (ln15 == 0) {
        #pragma unroll
        for (int mi = 0; mi < 2; ++mi)
            #pragma unroll
            for (int r = 0; r < 4; ++r)
                sred[w][mi * 16 + quad * 4 + r] = sm[mi][r];
    }
    __syncthreads();
    if (t < 32) rsum[t] = sred[0][t] + sred[1][t] + sred[2][t] + sred[3][t];
    __syncthreads();

    float scv = *scalep;
    #pragma unroll
    for (int mi = 0; mi < 2; ++mi) {
        #pragma unroll
        for (int r = 0; r < 4; ++r) {
            int q = mi * 16 + quad * 4 + r;
            float srs = scv / rsum[q];
            size_t rowbase = (size_t)(b * N + q0 + q) * C;
            #pragma unroll
            for (int ni = 0; ni < 8; ++ni) {
                size_t idx = rowbase + w * 128 + ni * 16 + ln15;
                out[idx] = acc[mi][ni][r] * srs + x[idx];
            }
        }
    }
}

// ---------------------------------------------------------------------------
extern "C" void kernel_launch(void* const* d_in, const int* in_sizes, int n_in,
                              void* d_out, int out_size, void* d_ws, size_t ws_size,
                              hipStream_t stream) {
    const float* x   = (const float*)d_in[0];
    const float* Wf  = (const float*)d_in[1];
    const float* bfv = (const float*)d_in[2];
    const float* Wg  = (const float*)d_in[3];
    const float* bgv = (const float*)d_in[4];
    const float* Wh  = (const float*)d_in[5];
    const float* bhv = (const float*)d_in[6];
    const float* sc  = (const float*)d_in[7];
    float* out = (float*)d_out;

    char* ws = (char*)d_ws;
    size_t off = 0;
    __hip_bfloat16* FFhi = (__hip_bfloat16*)(ws + off); off += (size_t)BB * N * A * 2;   // 2 MB
    __hip_bfloat16* FFlo = (__hip_bfloat16*)(ws + off); off += (size_t)BB * N * A * 2;   // 2 MB
    __hip_bfloat16* GFhi = (__hip_bfloat16*)(ws + off); off += (size_t)BB * N * A * 2;   // 2 MB
    __hip_bfloat16* GFlo = (__hip_bfloat16*)(ws + off); off += (size_t)BB * N * A * 2;   // 2 MB
    __hip_bfloat16* HFT  = (__hip_bfloat16*)(ws + off); off += (size_t)BB * C * N * 2;   // 16 MB
    char* Pbase          = (ws + off);                  off += (size_t)BB * N * N * 2;   // 128 MB (P dead; kept for XT overlay)
    off += (size_t)BB * N * 4;                                                            // (old rowsum slot, unused)
    __hip_bfloat16* WhT  = (__hip_bfloat16*)(ws + off); off += (size_t)C * C * 2;        // 512 KB
    __hip_bfloat16* WfThi = (__hip_bfloat16*)(ws + off); off += (size_t)A * C * 2;       // 64 KB
    __hip_bfloat16* WfTlo = (__hip_bfloat16*)(ws + off); off += (size_t)A * C * 2;       // 64 KB
    __hip_bfloat16* WgThi = (__hip_bfloat16*)(ws + off); off += (size_t)A * C * 2;       // 64 KB
    __hip_bfloat16* WgTlo = (__hip_bfloat16*)(ws + off); off += (size_t)A * C * 2;       // 64 KB
    // XT hi/lo [b][n][k] bf16 (16 MB each) overlay the TAIL of the old P region:
    // both are fully consumed by k_hm/k_fgm before anything else touches it.
    __hip_bfloat16* XThi = (__hip_bfloat16*)(Pbase + (size_t)BB * N * N * 2 - (size_t)BB * N * C * 2);
    __hip_bfloat16* XTlo = (__hip_bfloat16*)(Pbase + (size_t)BB * N * N * 2 - 2 * (size_t)BB * N * C * 2);

    // Wh [k=512][c=512] fp32 -> WhT [c][k] bf16
    k_trans<<<dim3(C / 64, C / 64, 1), dim3(256), 0, stream>>>(Wh, WhT, C, C);
    // X [b][k=512][n=4096] fp32 -> XThi/XTlo [b][n][k]
    k_trans2<<<dim3(N / 64, C / 64, BB), dim3(256), 0, stream>>>(x, XThi, XTlo, C, N);
    // Wf/Wg [k=512][a=64] fp32 -> [a][k] hi/lo
    k_trans2<<<dim3(A / 64, C / 64, 1), dim3(256), 0, stream>>>(Wf, WfThi, WfTlo, C, A);
    k_trans2<<<dim3(A / 64, C / 64, 1), dim3(256), 0, stream>>>(Wg, WgThi, WgTlo, C, A);
    k_hm<<<dim3(C / 128, N / 128, BB), dim3(256), 0, stream>>>(WhT, XThi, bhv, HFT);
    k_fgm<<<dim3((BB * N) / 64), dim3(256), 0, stream>>>(XThi, XTlo, WfThi, WfTlo, WgThi, WgTlo,
                                                         bfv, bgv, FFhi, FFlo, GFhi, GFlo);
    // fused S/softmax/PV/epilogue — P never touches HBM
    k_so<<<dim3(BB * (N / 32)), dim3(256), 0, stream>>>(GFhi, GFlo, FFhi, FFlo, HFT, x, sc, out);
}

// Round 2
// 431.522 us; speedup vs baseline: 1.1106x; 1.1106x over previous
//
#include <hip/hip_runtime.h>
#include <hip/hip_bf16.h>

// Problem constants (B,C,H,W = 4,512,64,64; A=64; N=H*W=4096)
constexpr int BB = 4;
constexpr int C  = 512;
constexpr int A  = 64;
constexpr int N  = 4096;

typedef __attribute__((ext_vector_type(8))) short s16x8;   // 8 bf16 (4 VGPRs)
typedef __attribute__((ext_vector_type(4))) float f32x4;   // 4 fp32 acc

#define MFMA_16x16x32_BF16(a, b, c) __builtin_amdgcn_mfma_f32_16x16x32_bf16((a), (b), (c), 0, 0, 0)

typedef __attribute__((address_space(3))) unsigned int lds_u32_t;
typedef const __attribute__((address_space(1))) unsigned int glb_u32_t;

__device__ __forceinline__ void gl2lds16(const void* g, void* l) {
    // async global->LDS, 16B/lane; LDS dest = wave-uniform base + lane*16
    __builtin_amdgcn_global_load_lds((glb_u32_t*)g, (lds_u32_t*)l, 16, 0, 0);
}

// ---------------------------------------------------------------------------
// K0a: transpose + fp32->bf16. src [z][K][M] fp32 -> dst [z][M][K] bf16.
__global__ __launch_bounds__(256) void k_trans(const float* __restrict__ src,
                                               __hip_bfloat16* __restrict__ dst,
                                               int K, int M) {
    __shared__ __hip_bfloat16 Ls[64][66];
    int m0 = blockIdx.x << 6, k0 = blockIdx.y << 6;
    size_t bo = (size_t)blockIdx.z * K * M;
    int t = threadIdx.x;
    int lm = t & 63, g = t >> 6;
    #pragma unroll
    for (int j = 0; j < 16; ++j) {
        int kk = j * 4 + g;
        Ls[kk][lm] = __float2bfloat16(src[bo + (size_t)(k0 + kk) * M + m0 + lm]);
    }
    __syncthreads();
    #pragma unroll
    for (int j = 0; j < 16; ++j) {
        int mm = j * 4 + g;
        dst[bo + (size_t)(m0 + mm) * K + k0 + lm] = Ls[lm][mm];
    }
}

// ---------------------------------------------------------------------------
// K0b: transpose + hi/lo bf16 split. src [z][K][M] fp32 -> dhi/dlo [z][M][K].
// fp32 LDS tile (65 pad -> conflict-free column reads), split at write.
__global__ __launch_bounds__(256) void k_trans2(const float* __restrict__ src,
                                                __hip_bfloat16* __restrict__ dhi,
                                                __hip_bfloat16* __restrict__ dlo,
                                                int K, int M) {
    __shared__ float Ls[64][65];
    int m0 = blockIdx.x << 6, k0 = blockIdx.y << 6;
    size_t bo = (size_t)blockIdx.z * K * M;
    int t = threadIdx.x;
    int lm = t & 63, g = t >> 6;
    #pragma unroll
    for (int j = 0; j < 16; ++j) {
        int kk = j * 4 + g;
        Ls[kk][lm] = src[bo + (size_t)(k0 + kk) * M + m0 + lm];
    }
    __syncthreads();
    #pragma unroll
    for (int j = 0; j < 16; ++j) {
        int mm = j * 4 + g;
        float v = Ls[lm][mm];
        __hip_bfloat16 h = __float2bfloat16(v);
        size_t idx = bo + (size_t)(m0 + mm) * K + k0 + lm;
        dhi[idx] = h;
        dlo[idx] = __float2bfloat16(v - __bfloat162float(h));
    }
}

// ---------------------------------------------------------------------------
// K1 v2 (k_fgm): f,g convs as ONE split-precision MFMA GEMM.
// out[row][col] , row = b*N+n (64/block), col = [f 0..63 | g 64..127].
// 3-product split (Ah*Bh + Al*Bh + Ah*Bl) -> ~2^-18 relative, matches the old
// fp32 path. Epilogue adds bias and emits hi/lo bf16 for k_so.
// grid 256 x 256 (4 waves: mh=w&1 over 2x32 rows, nh=w>>1 over 2x64 cols).
__global__ __launch_bounds__(256) void k_fgm(const __hip_bfloat16* __restrict__ XThi, const __hip_bfloat16* __restrict__ XTlo,
                                             const __hip_bfloat16* __restrict__ WfThi, const __hip_bfloat16* __restrict__ WfTlo,
                                             const __hip_bfloat16* __restrict__ WgThi, const __hip_bfloat16* __restrict__ WgTlo,
                                             const float* __restrict__ bfv, const float* __restrict__ bgv,
                                             __hip_bfloat16* __restrict__ FFhi, __hip_bfloat16* __restrict__ FFlo,
                                             __hip_bfloat16* __restrict__ GFhi, __hip_bfloat16* __restrict__ GFlo) {
    __shared__ __align__(16) __hip_bfloat16 Ah[64 * 32], Al[64 * 32];    // 4+4 KB
    __shared__ __align__(16) __hip_bfloat16 Bh[128 * 32], Bl[128 * 32];  // 8+8 KB
    int r0 = blockIdx.x << 6;           // global row base (b*N+n), 0..16320
    int t = threadIdx.x;
    int w = t >> 6, l = t & 63;
    int ln15 = l & 15, quad = l >> 4;
    int mh = w & 1, nh = w >> 1;

    f32x4 acc[2][4];
    #pragma unroll
    for (int mi = 0; mi < 2; ++mi)
        #pragma unroll
        for (int ni = 0; ni < 4; ++ni) acc[mi][ni] = (f32x4){0.f, 0.f, 0.f, 0.f};

    for (int kt = 0; kt < C; kt += 32) {
        {   // A tiles: 64 rows x 32 k, hi+lo, XOR-rotation swizzled segs
            int row = t >> 2, seg = t & 3;
            int gseg = (seg - (row >> 1)) & 3;
            size_t go = (size_t)(r0 + row) * C + kt + gseg * 8;
            gl2lds16(XThi + go, &Ah[t * 8]);
            gl2lds16(XTlo + go, &Al[t * 8]);
        }
        #pragma unroll
        for (int j = 0; j < 2; ++j) {   // B tiles: rows 0-63 = WfT, 64-127 = WgT
            int i = j * 256 + t;
            int row = i >> 2, seg = i & 3;
            int gseg = (seg - (row >> 1)) & 3;
            size_t go = (size_t)(row & 63) * C + kt + gseg * 8;
            const __hip_bfloat16* bh = j ? WgThi : WfThi;
            const __hip_bfloat16* bl = j ? WgTlo : WfTlo;
            gl2lds16(bh + go, &Bh[i * 8]);
            gl2lds16(bl + go, &Bl[i * 8]);
        }
        __syncthreads();
        s16x8 afh[2], afl[2], bfh[4], bfl[4];
        #pragma unroll
        for (int mi = 0; mi < 2; ++mi) {
            int row = mh * 32 + mi * 16 + ln15;
            int sw = ((quad + (row >> 1)) & 3) << 3;
            afh[mi] = *(const s16x8*)&Ah[row * 32 + sw];
            afl[mi] = *(const s16x8*)&Al[row * 32 + sw];
        }
        #pragma unroll
        for (int ni = 0; ni < 4; ++ni) {
            int row = nh * 64 + ni * 16 + ln15;
            int sw = ((quad + (row >> 1)) & 3) << 3;
            bfh[ni] = *(const s16x8*)&Bh[row * 32 + sw];
            bfl[ni] = *(const s16x8*)&Bl[row * 32 + sw];
        }
        #pragma unroll
        for (int mi = 0; mi < 2; ++mi)
            #pragma unroll
            for (int ni = 0; ni < 4; ++ni) {
                acc[mi][ni] = MFMA_16x16x32_BF16(afh[mi], bfh[ni], acc[mi][ni]);
                acc[mi][ni] = MFMA_16x16x32_BF16(afl[mi], bfh[ni], acc[mi][ni]);
                acc[mi][ni] = MFMA_16x16x32_BF16(afh[mi], bfl[ni], acc[mi][ni]);
            }
        __syncthreads();
    }

    #pragma unroll
    for (int mi = 0; mi < 2; ++mi) {
        #pragma unroll
        for (int r = 0; r < 4; ++r) {
            size_t grow = (size_t)(r0 + mh * 32 + mi * 16 + quad * 4 + r) * A;
            #pragma unroll
            for (int ni = 0; ni < 4; ++ni) {
                int col = nh * 64 + ni * 16 + ln15;     // nh selects f vs g (wave-uniform)
                if (col < A) {
                    float v = acc[mi][ni][r] + bfv[col];
                    __hip_bfloat16 h = __float2bfloat16(v);
                    FFhi[grow + col] = h;
                    FFlo[grow + col] = __float2bfloat16(v - __bfloat162float(h));
                } else {
                    int a = col - A;
                    float v = acc[mi][ni][r] + bgv[a];
                    __hip_bfloat16 h = __float2bfloat16(v);
                    GFhi[grow + a] = h;
                    GFlo[grow + a] = __float2bfloat16(v - __bfloat162float(h));
                }
            }
        }
    }
}

// ---------------------------------------------------------------------------
// K2: h conv as bf16 MFMA GEMM. HFT[c][n] = sum_k WhT[c][k]*XT[b][n][k] + bh[c].
// grid (C/128, N/128, BB) x 256.
__global__ __launch_bounds__(256) void k_hm(const __hip_bfloat16* __restrict__ WhT,
                                            const __hip_bfloat16* __restrict__ XT,
                                            const float* __restrict__ bhv,
                                            __hip_bfloat16* __restrict__ HFT) {
    __shared__ __align__(16) __hip_bfloat16 As[128 * 32];
    __shared__ __align__(16) __hip_bfloat16 Bs[128 * 32];
    int b  = blockIdx.z;
    int c0 = blockIdx.x << 7;
    int n0 = blockIdx.y << 7;
    int t = threadIdx.x;
    int w = t >> 6, l = t & 63;
    int ln15 = l & 15, quad = l >> 4;
    int mc = (w >> 1) << 6, nn = (w & 1) << 6;

    const __hip_bfloat16* Bb = XT + (size_t)b * N * C;   // [4096, 512]

    f32x4 acc[4][4];
    #pragma unroll
    for (int mi = 0; mi < 4; ++mi)
        #pragma unroll
        for (int ni = 0; ni < 4; ++ni) acc[mi][ni] = (f32x4){0.f, 0.f, 0.f, 0.f};

    for (int kt = 0; kt < C; kt += 32) {
        #pragma unroll
        for (int j = 0; j < 2; ++j) {
            int i = j * 256 + t;
            int row = i >> 2, seg = i & 3;
            int gseg = (seg - (row >> 1)) & 3;
            gl2lds16(WhT + ((size_t)(c0 + row) * C + kt + gseg * 8), &As[i * 8]);
        }
        #pragma unroll
        for (int j = 0; j < 2; ++j) {
            int i = j * 256 + t;
            int row = i >> 2, seg = i & 3;
            int gseg = (seg - (row >> 1)) & 3;
            gl2lds16(Bb + ((size_t)(n0 + row) * C + kt + gseg * 8), &Bs[i * 8]);
        }
        __syncthreads();
        s16x8 af[4], bf2[4];
        #pragma unroll
        for (int mi = 0; mi < 4; ++mi) {
            int row = mc + mi * 16 + ln15;
            int sw = ((quad + (row >> 1)) & 3) << 3;
            af[mi] = *(const s16x8*)&As[row * 32 + sw];
        }
        #pragma unroll
        for (int ni = 0; ni < 4; ++ni) {
            int row = nn + ni * 16 + ln15;
            int sw = ((quad + (row >> 1)) & 3) << 3;
            bf2[ni] = *(const s16x8*)&Bs[row * 32 + sw];
        }
        #pragma unroll
        for (int mi = 0; mi < 4; ++mi)
            #pragma unroll
            for (int ni = 0; ni < 4; ++ni)
                acc[mi][ni] = MFMA_16x16x32_BF16(af[mi], bf2[ni], acc[mi][ni]);
        __syncthreads();
    }

    #pragma unroll
    for (int mi = 0; mi < 4; ++mi) {
        #pragma unroll
        for (int r = 0; r < 4; ++r) {
            int c = c0 + mc + mi * 16 + quad * 4 + r;
            float bias = bhv[c];
            size_t rowbase = ((size_t)b * C + c) * N;
            #pragma unroll
            for (int ni = 0; ni < 4; ++ni) {
                int n = n0 + nn + ni * 16 + ln15;
                HFT[rowbase + n] = __float2bfloat16(acc[mi][ni][r] + bias);
            }
        }
    }
}

// ---------------------------------------------------------------------------
// K3 v2 (k_so): FUSED S -> exp -> PV -> epilogue. P never touches HBM.
//
// Round-1 post-mortem fixes (was 361 us, MfmaUtil 11% — VGPR spill + serial):
//  (1) __launch_bounds__(256,2): 256-VGPR budget (grid is exactly 2 blocks/CU
//      anyway) -> the h-fragment array no longer spills to scratch.
//  (2) Short H live ranges: h0[8] loaded before QK (latency hides under QK),
//      h1[8] loaded after the barrier (hides under PV-ks0's 16 MFMAs).
//  (3) P double-buffered -> ONE barrier per 64-key chunk (WAR on a P buffer
//      is protected by the NEXT iteration's barrier: a wave can't start
//      rewriting buf until all waves passed the barrier after its PV read).
//  (4) Cross-iteration F prefetch: next chunk's 4 F frags issued right after
//      the barrier, consumed by next QK -> F L2 latency off the critical path.
//
// Block = 32 queries x full C=512, batch b. 256 threads = 4 waves.
//   QK: wave w = key-quarter (keys w*16..w*16+15), split-precision 6 MFMA per
//       16x16 tile, exp (no max shift: s~N(0,64), max|s| << 88), P -> LDS.
//   PV: wave w = c-slice w*128..; H frags straight from global (each H row
//       consumed by exactly ONE wave; HFT[b] = 4 MB ~ one XCD's L2).
//
// P_lds swizzle: row q = 128 B; byte ^= (q&7)<<4. b16 writes 4-way (8 tiny
// stores, cheap); b128 reads 2-way = free. XOR flips bits 4-6; reads are
// 16B-aligned so the b128 read returns keys ks*32+quad*8+0..7 in order.
//
// Grid 512 = 4b x 128qs, XCD-pinned: batch b on XCDs {2b,2b+1} (bijective).
__global__ __launch_bounds__(256, 2) void k_so(const __hip_bfloat16* __restrict__ GFhi, const __hip_bfloat16* __restrict__ GFlo,
                                               const __hip_bfloat16* __restrict__ FFhi, const __hip_bfloat16* __restrict__ FFlo,
                                               const __hip_bfloat16* __restrict__ HFT,
                                               const float* __restrict__ x,
                                               const float* __restrict__ scalep,
                                               float* __restrict__ out) {
    __shared__ __align__(16) __hip_bfloat16 Pl[2][32 * 64];  // 2 x 4 KB P tiles
    __shared__ float sred[4][32];
    __shared__ float rsum[32];

    int id  = blockIdx.x;
    int xcd = id & 7;                         // HW round-robins blocks over 8 XCDs
    int b   = xcd >> 1;                       // batch pinned to an XCD pair
    int qs  = ((id >> 3) << 1) | (xcd & 1);   // 0..127, bijective with id
    int q0  = qs << 5;

    int t = threadIdx.x;
    int w = t >> 6, l = t & 63;
    int ln15 = l & 15, quad = l >> 4, q8 = quad << 3;

    const __hip_bfloat16* Fh = FFhi + (size_t)b * N * A;
    const __hip_bfloat16* Fl = FFlo + (size_t)b * N * A;
    const __hip_bfloat16* Hb = HFT  + (size_t)b * C * N;

    // G A-frags (queries, held all kernel): lane m=ln15, k=quad*8+j; hi+lo
    s16x8 ah[2][2], al[2][2];
    #pragma unroll
    for (int mi = 0; mi < 2; ++mi) {
        const __hip_bfloat16* gp = GFhi + (size_t)(b * N + q0 + mi * 16 + ln15) * A + q8;
        const __hip_bfloat16* lp = GFlo + (size_t)(b * N + q0 + mi * 16 + ln15) * A + q8;
        ah[mi][0] = *(const s16x8*)gp; ah[mi][1] = *(const s16x8*)(gp + 32);
        al[mi][0] = *(const s16x8*)lp; al[mi][1] = *(const s16x8*)(lp + 32);
    }

    f32x4 acc[2][8];                            // O acc: 32q x 128c per wave
    #pragma unroll
    for (int mi = 0; mi < 2; ++mi)
        #pragma unroll
        for (int ni = 0; ni < 8; ++ni) acc[mi][ni] = (f32x4){0.f, 0.f, 0.f, 0.f};
    float sm[2][4] = {{0.f,0.f,0.f,0.f},{0.f,0.f,0.f,0.f}};

    // Wave-invariant bases (elements): F row = kt + w*16 + ln15; H row (c) =
    // w*128 + ni*16 + ln15, column chunk base kt + ks*32 + quad*8.
    const __hip_bfloat16* fbase  = Fh + (size_t)(w * 16 + ln15) * A + q8;
    const __hip_bfloat16* flbase = Fl + (size_t)(w * 16 + ln15) * A + q8;
    const __hip_bfloat16* hbase  = Hb + (size_t)(w * 128 + ln15) * N + q8;

    // Prologue: F frags for kt=0
    s16x8 kh0 = *(const s16x8*)fbase;
    s16x8 kh1 = *(const s16x8*)(fbase + 32);
    s16x8 kl0 = *(const s16x8*)flbase;
    s16x8 kl1 = *(const s16x8*)(flbase + 32);

    for (int kt = 0; kt < N; kt += 64) {
        char* Pb = (char*)&Pl[(kt >> 6) & 1][0];
        // (1) H ks=0 frags issue now; latency hides under QK+exp
        s16x8 h0[8];
        #pragma unroll
        for (int ni = 0; ni < 8; ++ni)
            h0[ni] = *(const s16x8*)(hbase + (size_t)(ni * 16) * N + kt);
        // (2) S = G.F^T (split precision), exp, stash P in LDS
        #pragma unroll
        for (int mi = 0; mi < 2; ++mi) {
            f32x4 s = {0.f, 0.f, 0.f, 0.f};
            s = MFMA_16x16x32_BF16(ah[mi][0], kh0, s);
            s = MFMA_16x16x32_BF16(ah[mi][1], kh1, s);
            s = MFMA_16x16x32_BF16(al[mi][0], kh0, s);
            s = MFMA_16x16x32_BF16(al[mi][1], kh1, s);
            s = MFMA_16x16x32_BF16(ah[mi][0], kl0, s);
            s = MFMA_16x16x32_BF16(ah[mi][1], kl1, s);
            int key2 = (w * 16 + ln15) << 1;        // byte offset of this key
            #pragma unroll
            for (int r = 0; r < 4; ++r) {
                int q = mi * 16 + quad * 4 + r;
                float p = __expf(s[r]);             // no max shift (see header)
                __hip_bfloat16 pb = __float2bfloat16(p);
                sm[mi][r] += __bfloat162float(pb);  // sum what we actually use
                *(__hip_bfloat16*)(Pb + q * 128 + (key2 ^ ((q & 7) << 4))) = pb;
            }
        }
        __syncthreads();                            // P[buf] ready for all waves
        // (3) Prefetch next chunk's F frags (consumed by next iter's QK)
        int ktn = (kt + 64) & (N - 1);              // wrap: last-iter value unused
        s16x8 nh0 = *(const s16x8*)(fbase  + (size_t)ktn * A);
        s16x8 nh1 = *(const s16x8*)(fbase  + (size_t)ktn * A + 32);
        s16x8 nl0 = *(const s16x8*)(flbase + (size_t)ktn * A);
        s16x8 nl1 = *(const s16x8*)(flbase + (size_t)ktn * A + 32);
        // (4) H ks=1 frags; latency hides under PV ks=0
        s16x8 h1[8];
        #pragma unroll
        for (int ni = 0; ni < 8; ++ni)
            h1[ni] = *(const s16x8*)(hbase + (size_t)(ni * 16) * N + kt + 32);
        // (5) O += P @ H^T  (wave = its c-slice; full P tile from LDS)
        {
            s16x8 pa[2];
            #pragma unroll
            for (int mi = 0; mi < 2; ++mi) {
                int q = mi * 16 + ln15;
                pa[mi] = *(const s16x8*)(Pb + q * 128 + ((quad * 16) ^ ((q & 7) << 4)));
            }
            #pragma unroll
            for (int mi = 0; mi < 2; ++mi)
                #pragma unroll
                for (int ni = 0; ni < 8; ++ni)
                    acc[mi][ni] = MFMA_16x16x32_BF16(pa[mi], h0[ni], acc[mi][ni]);
        }
        {
            s16x8 pa[2];
            #pragma unroll
            for (int mi = 0; mi < 2; ++mi) {
                int q = mi * 16 + ln15;
                pa[mi] = *(const s16x8*)(Pb + q * 128 + ((64 + quad * 16) ^ ((q & 7) << 4)));
            }
            #pragma unroll
            for (int mi = 0; mi < 2; ++mi)
                #pragma unroll
                for (int ni = 0; ni < 8; ++ni)
                    acc[mi][ni] = MFMA_16x16x32_BF16(pa[mi], h1[ni], acc[mi][ni]);
        }
        // rotate prefetched F into place; NO second barrier (dbuf covers WAR)
        kh0 = nh0; kh1 = nh1; kl0 = nl0; kl1 = nl1;
    }

    // rowsum: per-lane partials -> 16-lane (key) reduce -> across waves via LDS
    #pragma unroll
    for (int mi = 0; mi < 2; ++mi)
        #pragma unroll
        for (int r = 0; r < 4; ++r)
            #pragma unroll
            for (int d = 1; d < 16; d <<= 1)
                sm[mi][r] += __shfl_xor(sm[mi][r], d, 64);
    if (ln15 == 0) {
        #pragma unroll
        for (int mi = 0; mi < 2; ++mi)
            #pragma unroll
            for (int r = 0; r < 4; ++r)
                sred[w][mi * 16 + quad * 4 + r] = sm[mi][r];
    }
    __syncthreads();
    if (t < 32) rsum[t] = sred[0][t] + sred[1][t] + sred[2][t] + sred[3][t];
    __syncthreads();

    float scv = *scalep;
    #pragma unroll
    for (int mi = 0; mi < 2; ++mi) {
        #pragma unroll
        for (int r = 0; r < 4; ++r) {
            int q = mi * 16 + quad * 4 + r;
            float srs = scv / rsum[q];
            size_t rowbase = (size_t)(b * N + q0 + q) * C;
            #pragma unroll
            for (int ni = 0; ni < 8; ++ni) {
                size_t idx = rowbase + w * 128 + ni * 16 + ln15;
                out[idx] = acc[mi][ni][r] * srs + x[idx];
            }
        }
    }
}

// ---------------------------------------------------------------------------
extern "C" void kernel_launch(void* const* d_in, const int* in_sizes, int n_in,
                              void* d_out, int out_size, void* d_ws, size_t ws_size,
                              hipStream_t stream) {
    const float* x   = (const float*)d_in[0];
    const float* Wf  = (const float*)d_in[1];
    const float* bfv = (const float*)d_in[2];
    const float* Wg  = (const float*)d_in[3];
    const float* bgv = (const float*)d_in[4];
    const float* Wh  = (const float*)d_in[5];
    const float* bhv = (const float*)d_in[6];
    const float* sc  = (const float*)d_in[7];
    float* out = (float*)d_out;

    char* ws = (char*)d_ws;
    size_t off = 0;
    __hip_bfloat16* FFhi = (__hip_bfloat16*)(ws + off); off += (size_t)BB * N * A * 2;   // 2 MB
    __hip_bfloat16* FFlo = (__hip_bfloat16*)(ws + off); off += (size_t)BB * N * A * 2;   // 2 MB
    __hip_bfloat16* GFhi = (__hip_bfloat16*)(ws + off); off += (size_t)BB * N * A * 2;   // 2 MB
    __hip_bfloat16* GFlo = (__hip_bfloat16*)(ws + off); off += (size_t)BB * N * A * 2;   // 2 MB
    __hip_bfloat16* HFT  = (__hip_bfloat16*)(ws + off); off += (size_t)BB * C * N * 2;   // 16 MB
    char* Pbase          = (ws + off);                  off += (size_t)BB * N * N * 2;   // 128 MB (dead; kept for XT overlay)
    off += (size_t)BB * N * 4;                                                            // (old rowsum slot, unused)
    __hip_bfloat16* WhT  = (__hip_bfloat16*)(ws + off); off += (size_t)C * C * 2;        // 512 KB
    __hip_bfloat16* WfThi = (__hip_bfloat16*)(ws + off); off += (size_t)A * C * 2;       // 64 KB
    __hip_bfloat16* WfTlo = (__hip_bfloat16*)(ws + off); off += (size_t)A * C * 2;       // 64 KB
    __hip_bfloat16* WgThi = (__hip_bfloat16*)(ws + off); off += (size_t)A * C * 2;       // 64 KB
    __hip_bfloat16* WgTlo = (__hip_bfloat16*)(ws + off); off += (size_t)A * C * 2;       // 64 KB
    // XT hi/lo [b][n][k] bf16 (16 MB each) overlay the TAIL of the old P region:
    // both are fully consumed by k_hm/k_fgm before anything else touches it.
    __hip_bfloat16* XThi = (__hip_bfloat16*)(Pbase + (size_t)BB * N * N * 2 - (size_t)BB * N * C * 2);
    __hip_bfloat16* XTlo = (__hip_bfloat16*)(Pbase + (size_t)BB * N * N * 2 - 2 * (size_t)BB * N * C * 2);

    // Wh [k=512][c=512] fp32 -> WhT [c][k] bf16
    k_trans<<<dim3(C / 64, C / 64, 1), dim3(256), 0, stream>>>(Wh, WhT, C, C);
    // X [b][k=512][n=4096] fp32 -> XThi/XTlo [b][n][k]
    k_trans2<<<dim3(N / 64, C / 64, BB), dim3(256), 0, stream>>>(x, XThi, XTlo, C, N);
    // Wf/Wg [k=512][a=64] fp32 -> [a][k] hi/lo
    k_trans2<<<dim3(A / 64, C / 64, 1), dim3(256), 0, stream>>>(Wf, WfThi, WfTlo, C, A);
    k_trans2<<<dim3(A / 64, C / 64, 1), dim3(256), 0, stream>>>(Wg, WgThi, WgTlo, C, A);
    k_hm<<<dim3(C / 128, N / 128, BB), dim3(256), 0, stream>>>(WhT, XThi, bhv, HFT);
    k_fgm<<<dim3((BB * N) / 64), dim3(256), 0, stream>>>(XThi, XTlo, WfThi, WfTlo, WgThi, WgTlo,
                                                         bfv, bgv, FFhi, FFlo, GFhi, GFlo);
    // fused S/softmax/PV/epilogue — P never touches HBM
    k_so<<<dim3(BB * (N / 32)), dim3(256), 0, stream>>>(GFhi, GFlo, FFhi, FFlo, HFT, x, sc, out);
}

// Round 3
// 325.417 us; speedup vs baseline: 1.4727x; 1.3261x over previous
//
#include <hip/hip_runtime.h>
#include <hip/hip_bf16.h>

// Problem constants (B,C,H,W = 4,512,64,64; A=64; N=H*W=4096)
constexpr int BB = 4;
constexpr int C  = 512;
constexpr int A  = 64;
constexpr int N  = 4096;

typedef __attribute__((ext_vector_type(8))) short s16x8;   // 8 bf16 (4 VGPRs)
typedef __attribute__((ext_vector_type(4))) float f32x4;   // 4 fp32 acc

#define MFMA_16x16x32_BF16(a, b, c) __builtin_amdgcn_mfma_f32_16x16x32_bf16((a), (b), (c), 0, 0, 0)

typedef __attribute__((address_space(3))) unsigned int lds_u32_t;
typedef const __attribute__((address_space(1))) unsigned int glb_u32_t;

__device__ __forceinline__ void gl2lds16(const void* g, void* l) {
    // async global->LDS, 16B/lane; LDS dest = wave-uniform base + lane*16
    __builtin_amdgcn_global_load_lds((glb_u32_t*)g, (lds_u32_t*)l, 16, 0, 0);
}

// ---------------------------------------------------------------------------
// K0a: transpose + fp32->bf16. src [z][K][M] fp32 -> dst [z][M][K] bf16.
__global__ __launch_bounds__(256) void k_trans(const float* __restrict__ src,
                                               __hip_bfloat16* __restrict__ dst,
                                               int K, int M) {
    __shared__ __hip_bfloat16 Ls[64][66];
    int m0 = blockIdx.x << 6, k0 = blockIdx.y << 6;
    size_t bo = (size_t)blockIdx.z * K * M;
    int t = threadIdx.x;
    int lm = t & 63, g = t >> 6;
    #pragma unroll
    for (int j = 0; j < 16; ++j) {
        int kk = j * 4 + g;
        Ls[kk][lm] = __float2bfloat16(src[bo + (size_t)(k0 + kk) * M + m0 + lm]);
    }
    __syncthreads();
    #pragma unroll
    for (int j = 0; j < 16; ++j) {
        int mm = j * 4 + g;
        dst[bo + (size_t)(m0 + mm) * K + k0 + lm] = Ls[lm][mm];
    }
}

// ---------------------------------------------------------------------------
// K0b: transpose + hi/lo bf16 split. src [z][K][M] fp32 -> dhi/dlo [z][M][K].
// fp32 LDS tile (65 pad -> conflict-free column reads), split at write.
__global__ __launch_bounds__(256) void k_trans2(const float* __restrict__ src,
                                                __hip_bfloat16* __restrict__ dhi,
                                                __hip_bfloat16* __restrict__ dlo,
                                                int K, int M) {
    __shared__ float Ls[64][65];
    int m0 = blockIdx.x << 6, k0 = blockIdx.y << 6;
    size_t bo = (size_t)blockIdx.z * K * M;
    int t = threadIdx.x;
    int lm = t & 63, g = t >> 6;
    #pragma unroll
    for (int j = 0; j < 16; ++j) {
        int kk = j * 4 + g;
        Ls[kk][lm] = src[bo + (size_t)(k0 + kk) * M + m0 + lm];
    }
    __syncthreads();
    #pragma unroll
    for (int j = 0; j < 16; ++j) {
        int mm = j * 4 + g;
        float v = Ls[lm][mm];
        __hip_bfloat16 h = __float2bfloat16(v);
        size_t idx = bo + (size_t)(m0 + mm) * K + k0 + lm;
        dhi[idx] = h;
        dlo[idx] = __float2bfloat16(v - __bfloat162float(h));
    }
}

// ---------------------------------------------------------------------------
// K1 v2 (k_fgm): f,g convs as ONE split-precision MFMA GEMM.
// out[row][col] , row = b*N+n (64/block), col = [f 0..63 | g 64..127].
// 3-product split (Ah*Bh + Al*Bh + Ah*Bl) -> ~2^-18 relative, matches the old
// fp32 path. Epilogue adds bias and emits hi/lo bf16 for k_so.
// grid 256 x 256 (4 waves: mh=w&1 over 2x32 rows, nh=w>>1 over 2x64 cols).
__global__ __launch_bounds__(256) void k_fgm(const __hip_bfloat16* __restrict__ XThi, const __hip_bfloat16* __restrict__ XTlo,
                                             const __hip_bfloat16* __restrict__ WfThi, const __hip_bfloat16* __restrict__ WfTlo,
                                             const __hip_bfloat16* __restrict__ WgThi, const __hip_bfloat16* __restrict__ WgTlo,
                                             const float* __restrict__ bfv, const float* __restrict__ bgv,
                                             __hip_bfloat16* __restrict__ FFhi, __hip_bfloat16* __restrict__ FFlo,
                                             __hip_bfloat16* __restrict__ GFhi, __hip_bfloat16* __restrict__ GFlo) {
    __shared__ __align__(16) __hip_bfloat16 Ah[64 * 32], Al[64 * 32];    // 4+4 KB
    __shared__ __align__(16) __hip_bfloat16 Bh[128 * 32], Bl[128 * 32];  // 8+8 KB
    int r0 = blockIdx.x << 6;           // global row base (b*N+n), 0..16320
    int t = threadIdx.x;
    int w = t >> 6, l = t & 63;
    int ln15 = l & 15, quad = l >> 4;
    int mh = w & 1, nh = w >> 1;

    f32x4 acc[2][4];
    #pragma unroll
    for (int mi = 0; mi < 2; ++mi)
        #pragma unroll
        for (int ni = 0; ni < 4; ++ni) acc[mi][ni] = (f32x4){0.f, 0.f, 0.f, 0.f};

    for (int kt = 0; kt < C; kt += 32) {
        {   // A tiles: 64 rows x 32 k, hi+lo, XOR-rotation swizzled segs
            int row = t >> 2, seg = t & 3;
            int gseg = (seg - (row >> 1)) & 3;
            size_t go = (size_t)(r0 + row) * C + kt + gseg * 8;
            gl2lds16(XThi + go, &Ah[t * 8]);
            gl2lds16(XTlo + go, &Al[t * 8]);
        }
        #pragma unroll
        for (int j = 0; j < 2; ++j) {   // B tiles: rows 0-63 = WfT, 64-127 = WgT
            int i = j * 256 + t;
            int row = i >> 2, seg = i & 3;
            int gseg = (seg - (row >> 1)) & 3;
            size_t go = (size_t)(row & 63) * C + kt + gseg * 8;
            const __hip_bfloat16* bh = j ? WgThi : WfThi;
            const __hip_bfloat16* bl = j ? WgTlo : WfTlo;
            gl2lds16(bh + go, &Bh[i * 8]);
            gl2lds16(bl + go, &Bl[i * 8]);
        }
        __syncthreads();
        s16x8 afh[2], afl[2], bfh[4], bfl[4];
        #pragma unroll
        for (int mi = 0; mi < 2; ++mi) {
            int row = mh * 32 + mi * 16 + ln15;
            int sw = ((quad + (row >> 1)) & 3) << 3;
            afh[mi] = *(const s16x8*)&Ah[row * 32 + sw];
            afl[mi] = *(const s16x8*)&Al[row * 32 + sw];
        }
        #pragma unroll
        for (int ni = 0; ni < 4; ++ni) {
            int row = nh * 64 + ni * 16 + ln15;
            int sw = ((quad + (row >> 1)) & 3) << 3;
            bfh[ni] = *(const s16x8*)&Bh[row * 32 + sw];
            bfl[ni] = *(const s16x8*)&Bl[row * 32 + sw];
        }
        #pragma unroll
        for (int mi = 0; mi < 2; ++mi)
            #pragma unroll
            for (int ni = 0; ni < 4; ++ni) {
                acc[mi][ni] = MFMA_16x16x32_BF16(afh[mi], bfh[ni], acc[mi][ni]);
                acc[mi][ni] = MFMA_16x16x32_BF16(afl[mi], bfh[ni], acc[mi][ni]);
                acc[mi][ni] = MFMA_16x16x32_BF16(afh[mi], bfl[ni], acc[mi][ni]);
            }
        __syncthreads();
    }

    #pragma unroll
    for (int mi = 0; mi < 2; ++mi) {
        #pragma unroll
        for (int r = 0; r < 4; ++r) {
            size_t grow = (size_t)(r0 + mh * 32 + mi * 16 + quad * 4 + r) * A;
            #pragma unroll
            for (int ni = 0; ni < 4; ++ni) {
                int col = nh * 64 + ni * 16 + ln15;     // nh selects f vs g (wave-uniform)
                if (col < A) {
                    float v = acc[mi][ni][r] + bfv[col];
                    __hip_bfloat16 h = __float2bfloat16(v);
                    FFhi[grow + col] = h;
                    FFlo[grow + col] = __float2bfloat16(v - __bfloat162float(h));
                } else {
                    int a = col - A;
                    float v = acc[mi][ni][r] + bgv[a];
                    __hip_bfloat16 h = __float2bfloat16(v);
                    GFhi[grow + a] = h;
                    GFlo[grow + a] = __float2bfloat16(v - __bfloat162float(h));
                }
            }
        }
    }
}

// ---------------------------------------------------------------------------
// K2: h conv as bf16 MFMA GEMM. HFT[c][n] = sum_k WhT[c][k]*XT[b][n][k] + bh[c].
// grid (C/128, N/128, BB) x 256.
__global__ __launch_bounds__(256) void k_hm(const __hip_bfloat16* __restrict__ WhT,
                                            const __hip_bfloat16* __restrict__ XT,
                                            const float* __restrict__ bhv,
                                            __hip_bfloat16* __restrict__ HFT) {
    __shared__ __align__(16) __hip_bfloat16 As[128 * 32];
    __shared__ __align__(16) __hip_bfloat16 Bs[128 * 32];
    int b  = blockIdx.z;
    int c0 = blockIdx.x << 7;
    int n0 = blockIdx.y << 7;
    int t = threadIdx.x;
    int w = t >> 6, l = t & 63;
    int ln15 = l & 15, quad = l >> 4;
    int mc = (w >> 1) << 6, nn = (w & 1) << 6;

    const __hip_bfloat16* Bb = XT + (size_t)b * N * C;   // [4096, 512]

    f32x4 acc[4][4];
    #pragma unroll
    for (int mi = 0; mi < 4; ++mi)
        #pragma unroll
        for (int ni = 0; ni < 4; ++ni) acc[mi][ni] = (f32x4){0.f, 0.f, 0.f, 0.f};

    for (int kt = 0; kt < C; kt += 32) {
        #pragma unroll
        for (int j = 0; j < 2; ++j) {
            int i = j * 256 + t;
            int row = i >> 2, seg = i & 3;
            int gseg = (seg - (row >> 1)) & 3;
            gl2lds16(WhT + ((size_t)(c0 + row) * C + kt + gseg * 8), &As[i * 8]);
        }
        #pragma unroll
        for (int j = 0; j < 2; ++j) {
            int i = j * 256 + t;
            int row = i >> 2, seg = i & 3;
            int gseg = (seg - (row >> 1)) & 3;
            gl2lds16(Bb + ((size_t)(n0 + row) * C + kt + gseg * 8), &Bs[i * 8]);
        }
        __syncthreads();
        s16x8 af[4], bf2[4];
        #pragma unroll
        for (int mi = 0; mi < 4; ++mi) {
            int row = mc + mi * 16 + ln15;
            int sw = ((quad + (row >> 1)) & 3) << 3;
            af[mi] = *(const s16x8*)&As[row * 32 + sw];
        }
        #pragma unroll
        for (int ni = 0; ni < 4; ++ni) {
            int row = nn + ni * 16 + ln15;
            int sw = ((quad + (row >> 1)) & 3) << 3;
            bf2[ni] = *(const s16x8*)&Bs[row * 32 + sw];
        }
        #pragma unroll
        for (int mi = 0; mi < 4; ++mi)
            #pragma unroll
            for (int ni = 0; ni < 4; ++ni)
                acc[mi][ni] = MFMA_16x16x32_BF16(af[mi], bf2[ni], acc[mi][ni]);
        __syncthreads();
    }

    #pragma unroll
    for (int mi = 0; mi < 4; ++mi) {
        #pragma unroll
        for (int r = 0; r < 4; ++r) {
            int c = c0 + mc + mi * 16 + quad * 4 + r;
            float bias = bhv[c];
            size_t rowbase = ((size_t)b * C + c) * N;
            #pragma unroll
            for (int ni = 0; ni < 4; ++ni) {
                int n = n0 + nn + ni * 16 + ln15;
                HFT[rowbase + n] = __float2bfloat16(acc[mi][ni][r] + bias);
            }
        }
    }
}

// ---------------------------------------------------------------------------
// K3 v3 (k_so): FUSED S -> exp -> PV -> epilogue. P never in HBM.
//
// Round-2 post-mortem: __syncthreads() drains vmcnt(0) every iteration (no
// load survives a barrier) and the allocator shrank to 112 VGPR (prefetch
// state never lived). Fixes:
//  (1) 64-query blocks, 512 threads (8 waves), grid 256 = 1 block/CU.
//      Halves H L2-traffic (each block reads HFT[b]=4MB); each H frag now
//      feeds 4 MFMAs. L2 floor ~80KB/CU/iter ~ 1430 cy.
//  (2) RAW barrier: inline-asm s_waitcnt lgkmcnt(0) + sched_barrier(0) +
//      __builtin_amdgcn_s_barrier(). LDS P-writes ordered; GLOBAL LOADS STAY
//      IN FLIGHT ACROSS THE BARRIER (T4). Race-free with ONE barrier/iter:
//      P dbuf alternates, writes always pre-barrier, reads post-barrier.
//  (3) Register-set-alternating macro unroll (hA/hB, fA/fB): true 1-iter
//      prefetch distance for H (8 loads) and F (4 loads), zero rotation
//      movs, all indices static (rule #20).
//
// Wave roles: QK: w=(qh=w>>2, kq=w&3): S[32q x 16k] = 12 MFMA (3-prod split).
//             PV: w owns c-slice w*64..+63: 32 MFMA from P_lds x H-regs.
// P_lds: [64q][64k] bf16, row=128B, swizzle byte ^= (q&7)<<4 (write 2B
// scatter cheap; read b128 2-way = free).
// Grid 256 = 4b x 64qs, XCD-pinned: batch b on XCDs {2b,2b+1} (bijective).
__global__ __launch_bounds__(512, 2) void k_so(const __hip_bfloat16* __restrict__ GFhi, const __hip_bfloat16* __restrict__ GFlo,
                                               const __hip_bfloat16* __restrict__ FFhi, const __hip_bfloat16* __restrict__ FFlo,
                                               const __hip_bfloat16* __restrict__ HFT,
                                               const float* __restrict__ x,
                                               const float* __restrict__ scalep,
                                               float* __restrict__ out) {
    __shared__ __align__(16) __hip_bfloat16 Pl[2][64 * 64];  // 2 x 8 KB P tiles
    __shared__ float sred[8][32];
    __shared__ float rsum[64];

    int id  = blockIdx.x;
    int xcd = id & 7;                         // HW round-robins blocks over XCDs
    int b   = xcd >> 1;                       // batch pinned to an XCD pair
    int qs  = ((id >> 3) << 1) | (xcd & 1);   // 0..63, bijective with id
    int q0  = qs << 6;

    int t = threadIdx.x;
    int w = t >> 6, l = t & 63;
    int ln15 = l & 15, quad = l >> 4, q8 = quad << 3;
    int qh = w >> 2, kq = w & 3;              // QK-phase wave role

    const __hip_bfloat16* Fh = FFhi + (size_t)b * N * A;
    const __hip_bfloat16* Fl = FFlo + (size_t)b * N * A;
    const __hip_bfloat16* Hb = HFT  + (size_t)b * C * N;

    // G A-frags (held all kernel): rows q0+qh*32+mi*16+ln15, hi+lo
    s16x8 ah[2][2], al[2][2];
    #pragma unroll
    for (int mi = 0; mi < 2; ++mi) {
        const __hip_bfloat16* gp = GFhi + (size_t)(b * N + q0 + qh * 32 + mi * 16 + ln15) * A + q8;
        const __hip_bfloat16* lp = GFlo + (size_t)(b * N + q0 + qh * 32 + mi * 16 + ln15) * A + q8;
        ah[mi][0] = *(const s16x8*)gp; ah[mi][1] = *(const s16x8*)(gp + 32);
        al[mi][0] = *(const s16x8*)lp; al[mi][1] = *(const s16x8*)(lp + 32);
    }

    f32x4 acc[4][4];                            // O acc: 64q x 64c per wave
    #pragma unroll
    for (int mi = 0; mi < 4; ++mi)
        #pragma unroll
        for (int ni = 0; ni < 4; ++ni) acc[mi][ni] = (f32x4){0.f, 0.f, 0.f, 0.f};
    float sm[2][4] = {{0.f,0.f,0.f,0.f},{0.f,0.f,0.f,0.f}};

    // Wave-invariant element bases
    const __hip_bfloat16* fhp  = Fh + (size_t)(kq * 16 + ln15) * A + q8;  // F row (key)
    const __hip_bfloat16* flp  = Fl + (size_t)(kq * 16 + ln15) * A + q8;
    const __hip_bfloat16* hptr = Hb + (size_t)(w * 64 + ln15) * N + q8;   // H row (c)
    int key2 = (kq * 16 + ln15) << 1;           // P byte column for QK store

    // Prologue: load H and F for kt=0 into set A
    s16x8 hA[2][4], hB[2][4], fA[4], fB[4];
    #pragma unroll
    for (int ks = 0; ks < 2; ++ks)
        #pragma unroll
        for (int ni = 0; ni < 4; ++ni)
            hA[ks][ni] = *(const s16x8*)(hptr + (size_t)(ni * 16) * N + ks * 32);
    fA[0] = *(const s16x8*)fhp;       fA[1] = *(const s16x8*)(fhp + 32);
    fA[2] = *(const s16x8*)flp;       fA[3] = *(const s16x8*)(flp + 32);

// One 64-key iteration. Issues next-iter H/F loads (into HN/FN) BEFORE the
// barrier; they stay in flight across it (raw s_barrier, no vmcnt drain).
#define KITER(KT, PBUF, HC, FC, HN, FN)                                        \
    {                                                                          \
        int ktn = ((KT) + 64) & (N - 1);  /* last-iter prefetch: harmless */   \
        _Pragma("unroll")                                                      \
        for (int ks = 0; ks < 2; ++ks)                                         \
            _Pragma("unroll")                                                  \
            for (int ni = 0; ni < 4; ++ni)                                     \
                HN[ks][ni] = *(const s16x8*)(hptr + (size_t)(ni * 16) * N + ktn + ks * 32); \
        FN[0] = *(const s16x8*)(fhp + (size_t)ktn * A);                        \
        FN[1] = *(const s16x8*)(fhp + (size_t)ktn * A + 32);                   \
        FN[2] = *(const s16x8*)(flp + (size_t)ktn * A);                        \
        FN[3] = *(const s16x8*)(flp + (size_t)ktn * A + 32);                   \
        _Pragma("unroll")                                                      \
        for (int mi = 0; mi < 2; ++mi) {                                       \
            f32x4 s = {0.f, 0.f, 0.f, 0.f};                                    \
            s = MFMA_16x16x32_BF16(ah[mi][0], FC[0], s);                       \
            s = MFMA_16x16x32_BF16(ah[mi][1], FC[1], s);                       \
            s = MFMA_16x16x32_BF16(al[mi][0], FC[0], s);                       \
            s = MFMA_16x16x32_BF16(al[mi][1], FC[1], s);                       \
            s = MFMA_16x16x32_BF16(ah[mi][0], FC[2], s);                       \
            s = MFMA_16x16x32_BF16(ah[mi][1], FC[3], s);                       \
            _Pragma("unroll")                                                  \
            for (int r = 0; r < 4; ++r) {                                      \
                int q = qh * 32 + mi * 16 + quad * 4 + r;                      \
                float p = __expf(s[r]);       /* no max shift (see header) */  \
                __hip_bfloat16 pb = __float2bfloat16(p);                       \
                sm[mi][r] += __bfloat162float(pb);                             \
                *(__hip_bfloat16*)((char*)(PBUF) + q * 128 + (key2 ^ ((q & 7) << 4))) = pb; \
            }                                                                  \
        }                                                                      \
        asm volatile("s_waitcnt lgkmcnt(0)" ::: "memory");                     \
        __builtin_amdgcn_sched_barrier(0);                                     \
        __builtin_amdgcn_s_barrier();     /* global loads stay in flight */    \
        _Pragma("unroll")                                                      \
        for (int ks = 0; ks < 2; ++ks) {                                       \
            s16x8 pa[4];                                                       \
            _Pragma("unroll")                                                  \
            for (int mi = 0; mi < 4; ++mi) {                                   \
                int q = mi * 16 + ln15;                                        \
                pa[mi] = *(const s16x8*)((char*)(PBUF) + q * 128 + ((ks * 64 + quad * 16) ^ ((q & 7) << 4))); \
            }                                                                  \
            _Pragma("unroll")                                                  \
            for (int mi = 0; mi < 4; ++mi)                                     \
                _Pragma("unroll")                                              \
                for (int ni = 0; ni < 4; ++ni)                                 \
                    acc[mi][ni] = MFMA_16x16x32_BF16(pa[mi], HC[ks][ni], acc[mi][ni]); \
        }                                                                      \
    }

    for (int kt = 0; kt < N; kt += 128) {
        KITER(kt,      (&Pl[0][0]), hA, fA, hB, fB);
        KITER(kt + 64, (&Pl[1][0]), hB, fB, hA, fA);
    }
#undef KITER

    // rowsum: lane partials -> 16-lane (key) reduce -> across kq waves via LDS
    #pragma unroll
    for (int mi = 0; mi < 2; ++mi)
        #pragma unroll
        for (int r = 0; r < 4; ++r)
            #pragma unroll
            for (int d = 1; d < 16; d <<= 1)
                sm[mi][r] += __shfl_xor(sm[mi][r], d, 64);
    if (ln15 == 0) {
        #pragma unroll
        for (int mi = 0; mi < 2; ++mi)
            #pragma unroll
            for (int r = 0; r < 4; ++r)
                sred[w][mi * 16 + quad * 4 + r] = sm[mi][r];
    }
    __syncthreads();
    if (t < 64) {
        int base = (t >> 5) << 2, ix = t & 31;
        rsum[t] = sred[base][ix] + sred[base + 1][ix] + sred[base + 2][ix] + sred[base + 3][ix];
    }
    __syncthreads();

    float scv = *scalep;
    #pragma unroll
    for (int mi = 0; mi < 4; ++mi) {
        #pragma unroll
        for (int r = 0; r < 4; ++r) {
            int q = mi * 16 + quad * 4 + r;
            float srs = scv / rsum[q];
            size_t rowbase = (size_t)(b * N + q0 + q) * C;
            #pragma unroll
            for (int ni = 0; ni < 4; ++ni) {
                size_t idx = rowbase + w * 64 + ni * 16 + ln15;
                out[idx] = acc[mi][ni][r] * srs + x[idx];
            }
        }
    }
}

// ---------------------------------------------------------------------------
extern "C" void kernel_launch(void* const* d_in, const int* in_sizes, int n_in,
                              void* d_out, int out_size, void* d_ws, size_t ws_size,
                              hipStream_t stream) {
    const float* x   = (const float*)d_in[0];
    const float* Wf  = (const float*)d_in[1];
    const float* bfv = (const float*)d_in[2];
    const float* Wg  = (const float*)d_in[3];
    const float* bgv = (const float*)d_in[4];
    const float* Wh  = (const float*)d_in[5];
    const float* bhv = (const float*)d_in[6];
    const float* sc  = (const float*)d_in[7];
    float* out = (float*)d_out;

    char* ws = (char*)d_ws;
    size_t off = 0;
    __hip_bfloat16* FFhi = (__hip_bfloat16*)(ws + off); off += (size_t)BB * N * A * 2;   // 2 MB
    __hip_bfloat16* FFlo = (__hip_bfloat16*)(ws + off); off += (size_t)BB * N * A * 2;   // 2 MB
    __hip_bfloat16* GFhi = (__hip_bfloat16*)(ws + off); off += (size_t)BB * N * A * 2;   // 2 MB
    __hip_bfloat16* GFlo = (__hip_bfloat16*)(ws + off); off += (size_t)BB * N * A * 2;   // 2 MB
    __hip_bfloat16* HFT  = (__hip_bfloat16*)(ws + off); off += (size_t)BB * C * N * 2;   // 16 MB
    char* Pbase          = (ws + off);                  off += (size_t)BB * N * N * 2;   // 128 MB (dead; kept for XT overlay)
    off += (size_t)BB * N * 4;                                                            // (old rowsum slot, unused)
    __hip_bfloat16* WhT  = (__hip_bfloat16*)(ws + off); off += (size_t)C * C * 2;        // 512 KB
    __hip_bfloat16* WfThi = (__hip_bfloat16*)(ws + off); off += (size_t)A * C * 2;       // 64 KB
    __hip_bfloat16* WfTlo = (__hip_bfloat16*)(ws + off); off += (size_t)A * C * 2;       // 64 KB
    __hip_bfloat16* WgThi = (__hip_bfloat16*)(ws + off); off += (size_t)A * C * 2;       // 64 KB
    __hip_bfloat16* WgTlo = (__hip_bfloat16*)(ws + off); off += (size_t)A * C * 2;       // 64 KB
    // XT hi/lo [b][n][k] bf16 (16 MB each) overlay the TAIL of the old P region:
    // both are fully consumed by k_hm/k_fgm before anything else touches it.
    __hip_bfloat16* XThi = (__hip_bfloat16*)(Pbase + (size_t)BB * N * N * 2 - (size_t)BB * N * C * 2);
    __hip_bfloat16* XTlo = (__hip_bfloat16*)(Pbase + (size_t)BB * N * N * 2 - 2 * (size_t)BB * N * C * 2);

    // Wh [k=512][c=512] fp32 -> WhT [c][k] bf16
    k_trans<<<dim3(C / 64, C / 64, 1), dim3(256), 0, stream>>>(Wh, WhT, C, C);
    // X [b][k=512][n=4096] fp32 -> XThi/XTlo [b][n][k]
    k_trans2<<<dim3(N / 64, C / 64, BB), dim3(256), 0, stream>>>(x, XThi, XTlo, C, N);
    // Wf/Wg [k=512][a=64] fp32 -> [a][k] hi/lo
    k_trans2<<<dim3(A / 64, C / 64, 1), dim3(256), 0, stream>>>(Wf, WfThi, WfTlo, C, A);
    k_trans2<<<dim3(A / 64, C / 64, 1), dim3(256), 0, stream>>>(Wg, WgThi, WgTlo, C, A);
    k_hm<<<dim3(C / 128, N / 128, BB), dim3(256), 0, stream>>>(WhT, XThi, bhv, HFT);
    k_fgm<<<dim3((BB * N) / 64), dim3(256), 0, stream>>>(XThi, XTlo, WfThi, WfTlo, WgThi, WgTlo,
                                                         bfv, bgv, FFhi, FFlo, GFhi, GFlo);
    // fused S/softmax/PV/epilogue — P never touches HBM
    k_so<<<dim3(BB * (N / 64)), dim3(512), 0, stream>>>(GFhi, GFlo, FFhi, FFlo, HFT, x, sc, out);
}